// Round 1
// baseline (25.088 us; speedup 1.0000x reference)
//
#include <hip/hip_runtime.h>
#include <math.h>
#include <limits.h>

#define NT 1024
#define NW (NT / 64)

__global__ __launch_bounds__(NT)
void predhead_kernel(const float* __restrict__ S,
                     const float* __restrict__ E,
                     const int* __restrict__ limit_p,
                     int* __restrict__ out, int B, int L) {
    extern __shared__ float lds[];
    float* sp = lds;        // L floats: softmax(start)
    float* ep = lds + L;    // L floats: softmax(end)
    __shared__ float rA[NW], rB[NW];
    __shared__ int   rI[NW];

    const int b    = blockIdx.x;
    const int tid  = threadIdx.x;
    const int lane = tid & 63;
    const int wv   = tid >> 6;
    const int limit = *limit_p;

    const float* srow = S + (size_t)b * L;
    const float* erow = E + (size_t)b * L;

    // ---- pass 1: row maxes (for stable softmax, matching reference) ----
    float ms = -INFINITY, me = -INFINITY;
    for (int i = tid; i < L; i += NT) {
        ms = fmaxf(ms, srow[i]);
        me = fmaxf(me, erow[i]);
    }
#pragma unroll
    for (int o = 32; o > 0; o >>= 1) {
        ms = fmaxf(ms, __shfl_down(ms, o, 64));
        me = fmaxf(me, __shfl_down(me, o, 64));
    }
    if (lane == 0) { rA[wv] = ms; rB[wv] = me; }
    __syncthreads();
    if (tid == 0) {
        float a = rA[0], c = rB[0];
        for (int w = 1; w < NW; ++w) { a = fmaxf(a, rA[w]); c = fmaxf(c, rB[w]); }
        rA[0] = a; rB[0] = c;
    }
    __syncthreads();
    ms = rA[0]; me = rB[0];
    __syncthreads();

    // ---- pass 2: exp(x - max) into LDS + sums ----
    float ssum = 0.f, esum = 0.f;
    for (int i = tid; i < L; i += NT) {
        float a = expf(srow[i] - ms);
        float c = expf(erow[i] - me);
        sp[i] = a; ep[i] = c;
        ssum += a; esum += c;
    }
#pragma unroll
    for (int o = 32; o > 0; o >>= 1) {
        ssum += __shfl_down(ssum, o, 64);
        esum += __shfl_down(esum, o, 64);
    }
    if (lane == 0) { rA[wv] = ssum; rB[wv] = esum; }
    __syncthreads();
    if (tid == 0) {
        float a = 0.f, c = 0.f;
        for (int w = 0; w < NW; ++w) { a += rA[w]; c += rB[w]; }
        rA[0] = a; rB[0] = c;
    }
    __syncthreads();
    const float Zs = rA[0], Ze = rB[0];
    __syncthreads();
    for (int i = tid; i < L; i += NT) {
        sp[i] = sp[i] / Zs;
        ep[i] = ep[i] / Ze;
    }
    __syncthreads();

    // ---- start pointer: argmax_i sp[i] * max_{j in [i, min(i+limit,L-1)]} ep[j] ----
    float bv = -INFINITY; int bi = INT_MAX;
    for (int i = tid; i < L; i += NT) {
        int jhi = i + limit; if (jhi > L - 1) jhi = L - 1;
        float m = ep[i];
        for (int j = i + 1; j <= jhi; ++j) m = fmaxf(m, ep[j]);
        float v = sp[i] * m;
        if (v > bv) { bv = v; bi = i; }   // ascending i -> keeps first max
    }
#pragma unroll
    for (int o = 32; o > 0; o >>= 1) {
        float ov = __shfl_down(bv, o, 64);
        int   oi = __shfl_down(bi, o, 64);
        if (ov > bv || (ov == bv && oi < bi)) { bv = ov; bi = oi; }
    }
    if (lane == 0) { rA[wv] = bv; rI[wv] = bi; }
    __syncthreads();
    if (tid == 0) {
        float v = rA[0]; int idx = rI[0];
        for (int w = 1; w < NW; ++w)
            if (rA[w] > v || (rA[w] == v && rI[w] < idx)) { v = rA[w]; idx = rI[w]; }
        out[b] = idx;
    }
    __syncthreads();

    // ---- end pointer: argmax_j ep[j] * max_{i in [max(0,j-limit), j]} sp[i] ----
    bv = -INFINITY; bi = INT_MAX;
    for (int j = tid; j < L; j += NT) {
        int ilo = j - limit; if (ilo < 0) ilo = 0;
        float m = sp[j];
        for (int i = j - 1; i >= ilo; --i) m = fmaxf(m, sp[i]);
        float v = ep[j] * m;
        if (v > bv) { bv = v; bi = j; }
    }
#pragma unroll
    for (int o = 32; o > 0; o >>= 1) {
        float ov = __shfl_down(bv, o, 64);
        int   oi = __shfl_down(bi, o, 64);
        if (ov > bv || (ov == bv && oi < bi)) { bv = ov; bi = oi; }
    }
    if (lane == 0) { rA[wv] = bv; rI[wv] = bi; }
    __syncthreads();
    if (tid == 0) {
        float v = rA[0]; int idx = rI[0];
        for (int w = 1; w < NW; ++w)
            if (rA[w] > v || (rA[w] == v && rI[w] < idx)) { v = rA[w]; idx = rI[w]; }
        out[B + b] = idx;
    }
}

extern "C" void kernel_launch(void* const* d_in, const int* in_sizes, int n_in,
                              void* d_out, int out_size, void* d_ws, size_t ws_size,
                              hipStream_t stream) {
    const float* S   = (const float*)d_in[0];
    const float* E   = (const float*)d_in[1];
    const int*   lim = (const int*)d_in[2];
    int* out = (int*)d_out;

    const int B = out_size / 2;          // tuple (start[B], end[B])
    const int L = in_sizes[0] / B;       // 3072

    const size_t shmem = (size_t)2 * L * sizeof(float);
    predhead_kernel<<<B, NT, shmem, stream>>>(S, E, lim, out, B, L);
}

// Round 2
// 22.242 us; speedup vs baseline: 1.1279x; 1.1279x over previous
//
#include <hip/hip_runtime.h>
#include <math.h>
#include <limits.h>

#define NT 1024
#define NW (NT / 64)

__global__ __launch_bounds__(NT)
void predhead_kernel(const float* __restrict__ S,
                     const float* __restrict__ E,
                     const int* __restrict__ limit_p,
                     int* __restrict__ out, int B, int L) {
    extern __shared__ float lds[];
    float* sl = lds;        // L floats: start logits
    float* el = lds + L;    // L floats: end logits
    __shared__ float rV0[NW], rV1[NW];
    __shared__ int   rI0[NW], rI1[NW];

    const int b    = blockIdx.x;
    const int tid  = threadIdx.x;
    const int lane = tid & 63;
    const int wv   = tid >> 6;
    const int limit = *limit_p;

    const float* srow = S + (size_t)b * L;
    const float* erow = E + (size_t)b * L;

    // ---- stage raw logits into LDS (softmax/exp are monotone: argmax of
    //      sp[i]*max ep[win] == argmax of s[i]+max e[win]) ----
    for (int i = tid; i < L; i += NT) {
        sl[i] = srow[i];
        el[i] = erow[i];
    }
    __syncthreads();

    // ---- fused dual argmax ----
    // start: argmax_i ( s[i] + max_{j in [i, min(i+limit,L-1)]} e[j] )
    // end:   argmax_j ( e[j] + max_{i in [max(0,j-limit), j]} s[i] )
    float bv0 = -INFINITY; int bi0 = INT_MAX;
    float bv1 = -INFINITY; int bi1 = INT_MAX;
    for (int i = tid; i < L; i += NT) {
        // forward window over e
        int jhi = i + limit; if (jhi > L - 1) jhi = L - 1;
        float mf = el[i];
        for (int j = i + 1; j <= jhi; ++j) mf = fmaxf(mf, el[j]);
        float v0 = sl[i] + mf;
        if (v0 > bv0) { bv0 = v0; bi0 = i; }   // ascending i keeps first max

        // backward window over s
        int ilo = i - limit; if (ilo < 0) ilo = 0;
        float mb = sl[i];
        for (int k = i - 1; k >= ilo; --k) mb = fmaxf(mb, sl[k]);
        float v1 = el[i] + mb;
        if (v1 > bv1) { bv1 = v1; bi1 = i; }
    }
#pragma unroll
    for (int o = 32; o > 0; o >>= 1) {
        float ov0 = __shfl_down(bv0, o, 64);
        int   oi0 = __shfl_down(bi0, o, 64);
        if (ov0 > bv0 || (ov0 == bv0 && oi0 < bi0)) { bv0 = ov0; bi0 = oi0; }
        float ov1 = __shfl_down(bv1, o, 64);
        int   oi1 = __shfl_down(bi1, o, 64);
        if (ov1 > bv1 || (ov1 == bv1 && oi1 < bi1)) { bv1 = ov1; bi1 = oi1; }
    }
    if (lane == 0) { rV0[wv] = bv0; rI0[wv] = bi0; rV1[wv] = bv1; rI1[wv] = bi1; }
    __syncthreads();
    if (tid == 0) {
        float v = rV0[0]; int idx = rI0[0];
        for (int w = 1; w < NW; ++w)
            if (rV0[w] > v || (rV0[w] == v && rI0[w] < idx)) { v = rV0[w]; idx = rI0[w]; }
        out[b] = idx;
        v = rV1[0]; idx = rI1[0];
        for (int w = 1; w < NW; ++w)
            if (rV1[w] > v || (rV1[w] == v && rI1[w] < idx)) { v = rV1[w]; idx = rI1[w]; }
        out[B + b] = idx;
    }
}

extern "C" void kernel_launch(void* const* d_in, const int* in_sizes, int n_in,
                              void* d_out, int out_size, void* d_ws, size_t ws_size,
                              hipStream_t stream) {
    const float* S   = (const float*)d_in[0];
    const float* E   = (const float*)d_in[1];
    const int*   lim = (const int*)d_in[2];
    int* out = (int*)d_out;

    const int B = out_size / 2;          // tuple (start[B], end[B])
    const int L = in_sizes[0] / B;       // 3072

    const size_t shmem = (size_t)2 * L * sizeof(float);
    predhead_kernel<<<B, NT, shmem, stream>>>(S, E, lim, out, B, L);
}

// Round 3
// 12.044 us; speedup vs baseline: 2.0830x; 1.8468x over previous
//
#include <hip/hip_runtime.h>
#include <math.h>
#include <limits.h>

#define SEG 256
#define HALO 30

__device__ __forceinline__ unsigned long long shfl_down_u64(unsigned long long x, int o, int w) {
    unsigned int lo = (unsigned int)(x & 0xFFFFFFFFull);
    unsigned int hi = (unsigned int)(x >> 32);
    lo = (unsigned int)__shfl_down((int)lo, o, w);
    hi = (unsigned int)__shfl_down((int)hi, o, w);
    return ((unsigned long long)hi << 32) | (unsigned long long)lo;
}

// monotone float -> uint key (finite values), bigger float => bigger key
__device__ __forceinline__ unsigned int ordkey(float v) {
    unsigned int u = __float_as_uint(v);
    return (u & 0x80000000u) ? ~u : (u | 0x80000000u);
}

// pack (value, index) so that max-reduce picks larger value, then SMALLER index
__device__ __forceinline__ unsigned long long packvi(float v, int idx) {
    return ((unsigned long long)ordkey(v) << 32) |
           (unsigned long long)(0xFFFFFFFFu - (unsigned int)idx);
}

__global__ __launch_bounds__(SEG)
void predhead_partial(const float* __restrict__ S,
                      const float* __restrict__ E,
                      const int* __restrict__ limit_p,
                      unsigned long long* __restrict__ ws,
                      int B, int L, int G) {
    __shared__ float sE[SEG + HALO];             // e[S0 .. S0+SEG+HALO)   (clamped)
    __shared__ float sS[SEG + HALO];             // s[S0-HALO .. S0+SEG)   (clamped)
    __shared__ unsigned long long wk0[SEG / 64], wk1[SEG / 64];

    const int seg = blockIdx.x, row = blockIdx.y;
    const int tid = threadIdx.x, lane = tid & 63, wv = tid >> 6;
    const int S0  = seg * SEG;
    const int limit = *limit_p;
    const float* srow = S + (size_t)row * L;
    const float* erow = E + (size_t)row * L;
    const int i = S0 + tid;

    float v0 = -INFINITY, v1 = -INFINITY;

    if (limit == HALO) {
        // stage with clamped source indices; duplicated boundary values are
        // idempotent under max (duplicate only appears when the true window
        // already contains that boundary element)
        for (int k = tid; k < SEG + HALO; k += SEG) {
            int fe = S0 + k;        if (fe > L - 1) fe = L - 1;
            int fs = S0 - HALO + k; if (fs < 0)     fs = 0;
            sE[k] = erow[fe];
            sS[k] = srow[fs];
        }
        __syncthreads();

        if (i < L) {
            float w[HALO + 1];
            // start: s[i] + max_{j in [i, i+30]} e[j]
#pragma unroll
            for (int k = 0; k <= HALO; ++k) w[k] = sE[tid + k];
#pragma unroll
            for (int s = 1; s <= HALO; s <<= 1)
#pragma unroll
                for (int k = 0; k + s <= HALO; k += 2 * s) w[k] = fmaxf(w[k], w[k + s]);
            v0 = sS[tid + HALO] + w[0];

            // end: e[i] + max_{k in [i-30, i]} s[k]
#pragma unroll
            for (int k = 0; k <= HALO; ++k) w[k] = sS[tid + k];
#pragma unroll
            for (int s = 1; s <= HALO; s <<= 1)
#pragma unroll
                for (int k = 0; k + s <= HALO; k += 2 * s) w[k] = fmaxf(w[k], w[k + s]);
            v1 = sE[tid] + w[0];
        }
    } else if (i < L) {
        // generic runtime-limit fallback (global reads, rows are L2-resident)
        int jhi = i + limit; if (jhi > L - 1) jhi = L - 1;
        float mf = erow[i];
        for (int j = i + 1; j <= jhi; ++j) mf = fmaxf(mf, erow[j]);
        v0 = srow[i] + mf;
        int ilo = i - limit; if (ilo < 0) ilo = 0;
        float mb = srow[i];
        for (int k = i - 1; k >= ilo; --k) mb = fmaxf(mb, srow[k]);
        v1 = erow[i] + mb;
    }

    unsigned long long K0 = (i < L) ? packvi(v0, i) : 0ull;
    unsigned long long K1 = (i < L) ? packvi(v1, i) : 0ull;
#pragma unroll
    for (int o = 32; o > 0; o >>= 1) {
        unsigned long long a = shfl_down_u64(K0, o, 64); if (a > K0) K0 = a;
        unsigned long long b = shfl_down_u64(K1, o, 64); if (b > K1) K1 = b;
    }
    if (lane == 0) { wk0[wv] = K0; wk1[wv] = K1; }
    __syncthreads();
    if (tid == 0) {
#pragma unroll
        for (int w2 = 1; w2 < SEG / 64; ++w2) {
            if (wk0[w2] > K0) K0 = wk0[w2];
            if (wk1[w2] > K1) K1 = wk1[w2];
        }
        ws[(size_t)row * G + seg]       = K0;   // start partials: tasks [0, B)
        ws[(size_t)(B + row) * G + seg] = K1;   // end partials:   tasks [B, 2B)
    }
}

__global__ __launch_bounds__(256)
void predhead_final(const unsigned long long* __restrict__ ws,
                    int* __restrict__ out, int B, int G) {
    const int tid  = threadIdx.x;
    const int task = (blockIdx.x << 4) + (tid >> 4);   // one 16-lane group per task
    const int slot = tid & 15;
    const int ntask = 2 * B;

    unsigned long long K = 0ull;
    if (task < ntask) {
        for (int s = slot; s < G; s += 16) {
            unsigned long long a = ws[(size_t)task * G + s];
            if (a > K) K = a;
        }
    }
#pragma unroll
    for (int o = 8; o > 0; o >>= 1) {
        unsigned long long a = shfl_down_u64(K, o, 16);
        if (a > K) K = a;
    }
    if (slot == 0 && task < ntask) {
        out[task] = (int)(0xFFFFFFFFu - (unsigned int)(K & 0xFFFFFFFFull));
    }
}

extern "C" void kernel_launch(void* const* d_in, const int* in_sizes, int n_in,
                              void* d_out, int out_size, void* d_ws, size_t ws_size,
                              hipStream_t stream) {
    const float* S   = (const float*)d_in[0];
    const float* E   = (const float*)d_in[1];
    const int*   lim = (const int*)d_in[2];
    int* out = (int*)d_out;

    const int B = out_size / 2;          // tuple (start[B], end[B])
    const int L = in_sizes[0] / B;       // 3072
    const int G = (L + SEG - 1) / SEG;   // 12 segments per row

    unsigned long long* ws = (unsigned long long*)d_ws;

    predhead_partial<<<dim3(G, B), SEG, 0, stream>>>(S, E, lim, ws, B, L, G);
    const int nblk2 = (2 * B + 15) / 16;
    predhead_final<<<nblk2, 256, 0, stream>>>(ws, out, B, G);
}

// Round 4
// 9.299 us; speedup vs baseline: 2.6981x; 1.2953x over previous
//
#include <hip/hip_runtime.h>
#include <math.h>
#include <limits.h>

#define NT 1024
#define NW (NT / 64)
#define HALO 30
#define LFIX (3 * NT)   // fast path requires L == 3072

__device__ __forceinline__ unsigned long long shfl_down_u64(unsigned long long x, int o, int w) {
    unsigned int lo = (unsigned int)(x & 0xFFFFFFFFull);
    unsigned int hi = (unsigned int)(x >> 32);
    lo = (unsigned int)__shfl_down((int)lo, o, w);
    hi = (unsigned int)__shfl_down((int)hi, o, w);
    return ((unsigned long long)hi << 32) | (unsigned long long)lo;
}

// monotone float -> uint key (finite values), bigger float => bigger key
__device__ __forceinline__ unsigned int ordkey(float v) {
    unsigned int u = __float_as_uint(v);
    return (u & 0x80000000u) ? ~u : (u | 0x80000000u);
}

// pack (value, index): max-reduce picks larger value, then SMALLER index
__device__ __forceinline__ unsigned long long packvi(float v, int idx) {
    return ((unsigned long long)ordkey(v) << 32) |
           (unsigned long long)(0xFFFFFFFFu - (unsigned int)idx);
}

// One block per (row, direction) task. dir=0: start ptr, dir=1: end ptr.
//   dir0: v(i) = s[i] + max_{j in [i, min(i+30,L-1)]} e[j]      (window row = E)
//   dir1: v(j) = e[j] + max_{i in [max(0,j-30), j]}   s[i]      (window row = S)
// Staging sW[m] = wrow[clamp(m + off, 0, L-1)], off = dir ? -30 : 0, turns both
// into the SAME forward 31-window over sW. Clamp duplicates are idempotent
// under max (duplicate appears only when the true window contains that
// boundary element).
__global__ __launch_bounds__(NT)
void predhead_fused(const float* __restrict__ S,
                    const float* __restrict__ E,
                    const int* __restrict__ limit_p,
                    int* __restrict__ out, int B, int L) {
    __shared__ float sW[LFIX + HALO + 4];
    __shared__ unsigned long long wk[NW];

    const int bid = blockIdx.x;
    const int row = bid >> 1;
    const int dir = bid & 1;
    const int tid = threadIdx.x, lane = tid & 63, wv = tid >> 6;
    const int limit = *limit_p;

    const float* wrow = dir ? (S + (size_t)row * L) : (E + (size_t)row * L);
    const float* prow = dir ? (E + (size_t)row * L) : (S + (size_t)row * L);

    unsigned long long K = 0ull;

    if (limit == HALO && L == LFIX) {
        const int off = dir ? -HALO : 0;
        for (int m = tid; m < LFIX + HALO + 3; m += NT) {
            int f = m + off;
            f = f < 0 ? 0 : (f > LFIX - 1 ? LFIX - 1 : f);
            sW[m] = wrow[f];
        }
        __syncthreads();

        const int base = 3 * tid;          // this thread's 3 output positions
        float w[33];
#pragma unroll
        for (int k = 0; k < 33; ++k) w[k] = sW[base + k];

        // shared core: max(w[2..30]) via strided tree (w[0],w[1],w[31],w[32] untouched)
#pragma unroll
        for (int s = 1; s < 29; s <<= 1)
#pragma unroll
            for (int k = 2; k + s <= 30; k += 2 * s) w[k] = fmaxf(w[k], w[k + s]);
        const float core = w[2];

        const float m0 = fmaxf(fmaxf(w[0], w[1]), core);        // window [b, b+30]
        const float m1 = fmaxf(fmaxf(w[1], core), w[31]);       // window [b+1, b+31]
        const float m2 = fmaxf(fmaxf(core, w[31]), w[32]);      // window [b+2, b+32]

        const float v0 = prow[base]     + m0;
        const float v1 = prow[base + 1] + m1;
        const float v2 = prow[base + 2] + m2;

        float bv = v0; int bi = base;
        if (v1 > bv) { bv = v1; bi = base + 1; }   // strict > keeps first index
        if (v2 > bv) { bv = v2; bi = base + 2; }
        K = packvi(bv, bi);
    } else {
        // generic runtime-limit / shape fallback (global reads, L2-resident)
        for (int i = tid; i < L; i += NT) {
            float v;
            if (dir == 0) {
                int jhi = i + limit; if (jhi > L - 1) jhi = L - 1;
                float mf = wrow[i];
                for (int j = i + 1; j <= jhi; ++j) mf = fmaxf(mf, wrow[j]);
                v = prow[i] + mf;
            } else {
                int ilo = i - limit; if (ilo < 0) ilo = 0;
                float mb = wrow[i];
                for (int k = i - 1; k >= ilo; --k) mb = fmaxf(mb, wrow[k]);
                v = prow[i] + mb;
            }
            unsigned long long kk = packvi(v, i);
            if (kk > K) K = kk;
        }
    }

    // block-wide max of packed keys
#pragma unroll
    for (int o = 32; o > 0; o >>= 1) {
        unsigned long long a = shfl_down_u64(K, o, 64);
        if (a > K) K = a;
    }
    if (lane == 0) wk[wv] = K;
    __syncthreads();
    if (tid == 0) {
#pragma unroll
        for (int w2 = 1; w2 < NW; ++w2)
            if (wk[w2] > K) K = wk[w2];
        out[dir * B + row] = (int)(0xFFFFFFFFu - (unsigned int)(K & 0xFFFFFFFFull));
    }
}

extern "C" void kernel_launch(void* const* d_in, const int* in_sizes, int n_in,
                              void* d_out, int out_size, void* d_ws, size_t ws_size,
                              hipStream_t stream) {
    const float* S   = (const float*)d_in[0];
    const float* E   = (const float*)d_in[1];
    const int*   lim = (const int*)d_in[2];
    int* out = (int*)d_out;

    const int B = out_size / 2;          // tuple (start[B], end[B])
    const int L = in_sizes[0] / B;       // 3072

    predhead_fused<<<2 * B, NT, 0, stream>>>(S, E, lim, out, B, L);
}

// Round 5
// 9.293 us; speedup vs baseline: 2.6996x; 1.0006x over previous
//
#include <hip/hip_runtime.h>
#include <math.h>
#include <limits.h>

#define NT 1024
#define NW (NT / 64)
#define HALO 30
#define LFIX (3 * NT)   // fast path requires L == 3072
#define PAD 32          // front pad in sW; keeps bulk copy 16B-aligned

__device__ __forceinline__ unsigned long long shfl_down_u64(unsigned long long x, int o, int w) {
    unsigned int lo = (unsigned int)(x & 0xFFFFFFFFull);
    unsigned int hi = (unsigned int)(x >> 32);
    lo = (unsigned int)__shfl_down((int)lo, o, w);
    hi = (unsigned int)__shfl_down((int)hi, o, w);
    return ((unsigned long long)hi << 32) | (unsigned long long)lo;
}

// monotone float -> uint key (finite values), bigger float => bigger key
__device__ __forceinline__ unsigned int ordkey(float v) {
    unsigned int u = __float_as_uint(v);
    return (u & 0x80000000u) ? ~u : (u | 0x80000000u);
}

// pack (value, index): max-reduce picks larger value, then SMALLER index
__device__ __forceinline__ unsigned long long packvi(float v, int idx) {
    return ((unsigned long long)ordkey(v) << 32) |
           (unsigned long long)(0xFFFFFFFFu - (unsigned int)idx);
}

// One block per (row, direction) task. dir=0: start ptr, dir=1: end ptr.
//   dir0: v(i) = s[i] + max_{j in [i, min(i+30,L-1)]} e[j]    (window row = E)
//   dir1: v(j) = e[j] + max_{i in [max(0,j-30), j]}   s[i]    (window row = S)
// Staging is dir-independent: sW[PAD+m] = wrow[m], with 30 clamp-pad values
// (wrow[0]) at sW[2..31] and 30 (wrow[L-1]) at sW[PAD+L..PAD+L+29]. Window
// reads use base offset PAD (dir0) or PAD-30 (dir1). Clamp duplicates are
// idempotent under max.
__global__ __launch_bounds__(NT)
void predhead_fused(const float* __restrict__ S,
                    const float* __restrict__ E,
                    const int* __restrict__ limit_p,
                    int* __restrict__ out, int B, int L) {
    __shared__ float sW[PAD + LFIX + HALO + 2];
    __shared__ unsigned long long wk[NW];

    const int bid = blockIdx.x;
    const int row = bid >> 1;
    const int dir = bid & 1;
    const int tid = threadIdx.x, lane = tid & 63, wv = tid >> 6;

    const float* wrow = dir ? (S + (size_t)row * L) : (E + (size_t)row * L);
    const float* prow = dir ? (E + (size_t)row * L) : (S + (size_t)row * L);

    const int limit = *limit_p;   // issued early; latency hides under staging

    unsigned long long K = 0ull;
    const int base = 3 * tid;

    float p0 = 0.f, p1 = 0.f, p2 = 0.f;
    if (L == LFIX) {
        // one-shot aligned staging: 768 threads copy the row as float4,
        // the next 60 threads write the clamp pads
        if (tid < LFIX / 4) {
            const float4 v = *reinterpret_cast<const float4*>(wrow + 4 * tid);
            *reinterpret_cast<float4*>(&sW[PAD + 4 * tid]) = v;
        } else if (tid < LFIX / 4 + HALO) {
            sW[2 + (tid - LFIX / 4)] = wrow[0];                      // sW[2..31]
        } else if (tid < LFIX / 4 + 2 * HALO) {
            sW[PAD + LFIX + (tid - LFIX / 4 - HALO)] = wrow[LFIX - 1];
        }
        // prow preload (independent of LDS) — overlaps the barrier wait
        p0 = prow[base]; p1 = prow[base + 1]; p2 = prow[base + 2];
        __syncthreads();
    }

    if (L == LFIX && limit == HALO) {
        const int woff = (dir ? (PAD - HALO) : PAD) + base;
        float w[33];
#pragma unroll
        for (int k = 0; k < 33; ++k) w[k] = sW[woff + k];

        // shared core: max(w[2..30]) via strided tree (w[0],w[1],w[31],w[32] untouched)
#pragma unroll
        for (int s = 1; s < 29; s <<= 1)
#pragma unroll
            for (int k = 2; k + s <= 30; k += 2 * s) w[k] = fmaxf(w[k], w[k + s]);
        const float core = w[2];

        const float m0 = fmaxf(fmaxf(w[0], w[1]), core);   // window [base,   base+30]
        const float m1 = fmaxf(fmaxf(w[1], core), w[31]);  // window [base+1, base+31]
        const float m2 = fmaxf(fmaxf(core, w[31]), w[32]); // window [base+2, base+32]

        const float v0 = p0 + m0;
        const float v1 = p1 + m1;
        const float v2 = p2 + m2;

        float bv = v0; int bi = base;
        if (v1 > bv) { bv = v1; bi = base + 1; }   // strict > keeps first index
        if (v2 > bv) { bv = v2; bi = base + 2; }
        K = packvi(bv, bi);
    } else {
        // generic runtime-limit / shape fallback (global reads, L2-resident)
        for (int i = tid; i < L; i += NT) {
            float v;
            if (dir == 0) {
                int jhi = i + limit; if (jhi > L - 1) jhi = L - 1;
                float mf = wrow[i];
                for (int j = i + 1; j <= jhi; ++j) mf = fmaxf(mf, wrow[j]);
                v = prow[i] + mf;
            } else {
                int ilo = i - limit; if (ilo < 0) ilo = 0;
                float mb = wrow[i];
                for (int k = i - 1; k >= ilo; --k) mb = fmaxf(mb, wrow[k]);
                v = prow[i] + mb;
            }
            unsigned long long kk = packvi(v, i);
            if (kk > K) K = kk;
        }
    }

    // wave-level max of packed keys
#pragma unroll
    for (int o = 32; o > 0; o >>= 1) {
        unsigned long long a = shfl_down_u64(K, o, 64);
        if (a > K) K = a;
    }
    if (lane == 0) wk[wv] = K;
    __syncthreads();

    // cross-wave reduce, lane-parallel in wave 0
    if (wv == 0) {
        K = wk[lane & (NW - 1)];
#pragma unroll
        for (int o = NW / 2; o > 0; o >>= 1) {
            unsigned long long a = shfl_down_u64(K, o, NW);
            if (a > K) K = a;
        }
        if (lane == 0)
            out[dir * B + row] = (int)(0xFFFFFFFFu - (unsigned int)(K & 0xFFFFFFFFull));
    }
}

extern "C" void kernel_launch(void* const* d_in, const int* in_sizes, int n_in,
                              void* d_out, int out_size, void* d_ws, size_t ws_size,
                              hipStream_t stream) {
    const float* S   = (const float*)d_in[0];
    const float* E   = (const float*)d_in[1];
    const int*   lim = (const int*)d_in[2];
    int* out = (int*)d_out;

    const int B = out_size / 2;          // tuple (start[B], end[B])
    const int L = in_sizes[0] / B;       // 3072

    predhead_fused<<<2 * B, NT, 0, stream>>>(S, E, lim, out, B, L);
}